// Round 9
// baseline (321.786 us; speedup 1.0000x reference)
//
#include <hip/hip_runtime.h>
#include <hip/hip_bf16.h>

#define BB 256
#define LL 200
#define CC 4
#define HH 128
#define G3 384

typedef short bf16x8 __attribute__((ext_vector_type(8)));
typedef float f32x4 __attribute__((ext_vector_type(4)));

#define MFMA16(a, b, c) __builtin_amdgcn_mfma_f32_16x16x32_bf16((a), (b), (c), 0, 0, 0)

__device__ __forceinline__ short bf16_rne(float x) {
    union { float f; unsigned u; } v; v.f = x;
    unsigned r = v.u + 0x7FFFu + ((v.u >> 16) & 1u);
    return (short)(r >> 16);
}
__device__ __forceinline__ float bf16_tof(short b) {
    union { unsigned u; float f; } v; v.u = ((unsigned)(unsigned short)b) << 16;
    return v.f;
}
__device__ __forceinline__ float rcp_(float x) { return __builtin_amdgcn_rcpf(x); }
__device__ __forceinline__ float sigm_(float x) { return rcp_(1.0f + __expf(-x)); }
__device__ __forceinline__ float tanhf_(float x) { return 2.0f * rcp_(1.0f + __expf(-2.0f * x)) - 1.0f; }

__device__ __forceinline__ uint2 pack4(float4 v) {
    uint2 p;
    p.x = (unsigned)(unsigned short)bf16_rne(v.x) | ((unsigned)(unsigned short)bf16_rne(v.y) << 16);
    p.y = (unsigned)(unsigned short)bf16_rne(v.z) | ((unsigned)(unsigned short)bf16_rne(v.w) << 16);
    return p;
}

// ---------------------------------------------------------------------------
// lengths from timeline_mask (bool-dtype detection, verified R1-R7)
// ---------------------------------------------------------------------------
__global__ void compute_lens_kernel(const unsigned char* __restrict__ mask8,
                                    int* __restrict__ lens) {
    __shared__ int bad;
    int b = threadIdx.x;
    if (b == 0) bad = 0;
    __syncthreads();
    int cnt8 = 0, prev = 0, mono = 1;
    for (int t = 0; t < LL; ++t) {
        int v = mask8[b * LL + t] ? 1 : 0;
        cnt8 += (v == 0);
        if (v < prev) mono = 0;
        prev = v;
    }
    if (!mono) atomicAdd(&bad, 1);
    __syncthreads();
    int len;
    if (bad == 0) {
        len = cnt8;
    } else {
        const int* m32 = (const int*)mask8;
        int c = 0;
        for (int t = 0; t < LL; ++t) c += (m32[b * LL + t] == 0);
        len = c;
    }
    if (len < 1) len = 1;
    if (len > LL) len = LL;
    lens[b] = len;
}

// ---------------------------------------------------------------------------
// weight split: bf16 hi for W_ih and W_hh
// ---------------------------------------------------------------------------
__global__ void wsplit_kernel(const float* __restrict__ Wih, const float* __restrict__ Whh,
                              short* __restrict__ wih_hi, short* __restrict__ whh_hi) {
    int i = blockIdx.x * 256 + threadIdx.x;   // 768 blocks -> 196608
    wih_hi[i] = bf16_rne(Wih[i]);
    whh_hi[i] = bf16_rne(Whh[i]);
}

// ---------------------------------------------------------------------------
// Fused GRU: grid (32 bt x 4 c) = 128 WGs, 256 thr = 4 WAVES, M=8 batches.
// KEY CHANGE vs R7: 4 waves/WG -> 1 wave/SIMD -> 512-VGPR budget. Weight
// demand (192) + working set (~150) now FITS -> scratch spill impossible.
// Wave w owns gate-cols {w*16+l15, (w+4)*16+l15} per gate via
//   NT(q) = (q>>1)*8 + w + 4*(q&1),  q = gate*2 + p, q=0..5.
// Weights parked via identity MFMA (D=0*0+C, bit-exact: packed-bf16 words
// are normal f32 bit patterns) -> MFMA-defined, not rematerializable.
// h: hi+lo shorts in LDS, double-buffered, writer-side split.
// x: hi-only bf16 staged cooperatively into LDS one step ahead; xproj for
//    s+1 computed during step s (off the recurrence chain).
// ---------------------------------------------------------------------------
__global__ __launch_bounds__(256, 1) void gru_fused_kernel(
    const float* __restrict__ seqs,    // (B,L,C,H)
    const int*   __restrict__ lens,    // (B,)
    const short* __restrict__ wih_hi,  // (C,384,128) bf16
    const short* __restrict__ whh_hi,  // (C,384,128) bf16
    const float* __restrict__ b_ih,    // (C,384)
    const float* __restrict__ b_hh,    // (C,384)
    float*       __restrict__ out)     // (C,B,L,H)
{
    const int bt = blockIdx.x;             // 0..31
    const int c  = blockIdx.y;             // 0..3
    const int bbase = bt * 8;
    const int tid = threadIdx.x;           // 0..255
    const int w = tid >> 6;                // wave 0..3
    const int l = tid & 63;
    const int l15 = l & 15, g = l >> 4;
    const int lb  = l15 & 7;               // A-row batch (replicated 2x)
    const int l4  = g;

    __shared__ __align__(16) short hA[2][2][8][136];   // [buf][hi/lo][batch][k]
    __shared__ __align__(16) short xs[2][8][136];      // [buf][batch][k] bf16 hi

    // ---- park weight fragments (identity MFMA => not rematerializable) ----
    // B-frag for NT(q): row NT*16+l15, k = ks*32 + g*8 + j
    bf16x8 BH[6][4], WI[6][4];
    {
        const bf16x8 z8 = (bf16x8){0, 0, 0, 0, 0, 0, 0, 0};
        #pragma unroll
        for (int q = 0; q < 6; ++q) {
            const int NT = (q >> 1) * 8 + w + 4 * (q & 1);
            #pragma unroll
            for (int ks = 0; ks < 4; ++ks) {
                size_t off = (size_t)(c * G3 + NT * 16 + l15) * HH + ks * 32 + g * 8;
                f32x4 th = *(const f32x4*)(const void*)(whh_hi + off);
                f32x4 ti = *(const f32x4*)(const void*)(wih_hi + off);
                f32x4 ph = MFMA16(z8, z8, th);
                f32x4 pi = MFMA16(z8, z8, ti);
                __builtin_memcpy(&BH[q][ks], &ph, 16);
                __builtin_memcpy(&WI[q][ks], &pi, 16);
            }
        }
    }

    // ---- stager state: thread stages batch row 2w+(l>>5), 4 floats ----
    const int bsl = 2 * w + (l >> 5);       // 0..7
    const int bs  = bbase + bsl;
    const int k0s = (l & 31) * 4;           // 0..124
    const int lenS = lens[bs];
    const float* srow = seqs + ((size_t)bs * LL * CC + c) * HH + k0s;
    int ts0 = LL - lenS;
    int ts1 = ts0 + 1; if (ts1 >= LL) ts1 -= LL;
    float4 xr0 = *(const float4*)(srow + (size_t)ts0 * (CC * HH));
    float4 xr1 = *(const float4*)(srow + (size_t)ts1 * (CC * HH));
    int txs = ts1 + 1; if (txs >= LL) txs -= LL;   // t for s=2

    // ---- biases (2 cols per lane: col0 = w*16+l15, col1 = col0+64) ----
    const int col0 = w * 16 + l15;
    float bRs[2], bZs[2], bHN[2], bIN[2];
    #pragma unroll
    for (int p = 0; p < 2; ++p) {
        int cp = col0 + p * 64;
        bRs[p] = b_hh[c * G3 + cp]       + b_ih[c * G3 + cp];
        bZs[p] = b_hh[c * G3 + 128 + cp] + b_ih[c * G3 + 128 + cp];
        bHN[p] = b_hh[c * G3 + 256 + cp];
        bIN[p] = b_ih[c * G3 + 256 + cp];
    }

    // ---- per-lane output row state (valid for l4<2: batches l4*4+r) ----
    int lenr[4], tcur[4];
    #pragma unroll
    for (int r = 0; r < 4; ++r) {
        int b = bbase + (l4 & 1) * 4 + r;
        lenr[r] = lens[b];
        tcur[r] = LL - lenr[r];
    }
    float hold[2][4];
    #pragma unroll
    for (int p = 0; p < 2; ++p)
        #pragma unroll
        for (int r = 0; r < 4; ++r) hold[p][r] = 0.f;

    // ---- zero h buffer 0 ----
    for (int i = tid; i < 1088; i += 256) ((int*)hA[0])[i] = 0;

    // ---- stage x(0)->xs[0], x(1)->xs[1] ----
    *(uint2*)&xs[0][bsl][k0s] = pack4(xr0);
    *(uint2*)&xs[1][bsl][k0s] = pack4(xr1);
    __syncthreads();

    // ---- xacc(0) from xs[0] ----
    f32x4 xacc[6];
    #pragma unroll
    for (int p = 0; p < 2; ++p) {
        xacc[0 + p] = (f32x4){bRs[p], bRs[p], bRs[p], bRs[p]};
        xacc[2 + p] = (f32x4){bZs[p], bZs[p], bZs[p], bZs[p]};
        xacc[4 + p] = (f32x4){bIN[p], bIN[p], bIN[p], bIN[p]};
    }
    {
        bf16x8 xh[4];
        #pragma unroll
        for (int ks = 0; ks < 4; ++ks)
            xh[ks] = *(const bf16x8*)&xs[0][lb][ks * 32 + g * 8];
        #pragma unroll
        for (int ks = 0; ks < 4; ++ks) {
            #pragma unroll
            for (int q = 0; q < 6; ++q)
                xacc[q] = MFMA16(xh[ks], WI[q][ks], xacc[q]);
        }
    }
    // issue x(2)
    float4 xraw = *(const float4*)(srow + (size_t)txs * (CC * HH));
    txs = (txs + 1 == LL) ? 0 : txs + 1;

    __syncthreads();   // protect xs[0] from step-0 overwrite

    // =======================  main loop  =======================
    for (int si = 0; si < LL; ++si) {
        const int hb = si & 1, hn = hb ^ 1;

        // 1. h A-frags (hi+lo)
        bf16x8 ah[4], al[4];
        #pragma unroll
        for (int ks = 0; ks < 4; ++ks) {
            ah[ks] = *(const bf16x8*)&hA[hb][0][lb][ks * 32 + g * 8];
            al[ks] = *(const bf16x8*)&hA[hb][1][lb][ks * 32 + g * 8];
        }
        // 2. x(si+1) A-frags (hi only, pre-staged bf16)
        bf16x8 xh[4];
        #pragma unroll
        for (int ks = 0; ks < 4; ++ks)
            xh[ks] = *(const bf16x8*)&xs[hn][lb][ks * 32 + g * 8];

        // 3. rec MFMAs: racc = (h_hi + h_lo) . W_hh_hi  (dep distance 6)
        f32x4 racc[6];
        #pragma unroll
        for (int p = 0; p < 2; ++p) {
            racc[0 + p] = (f32x4){0.f, 0.f, 0.f, 0.f};
            racc[2 + p] = (f32x4){0.f, 0.f, 0.f, 0.f};
            racc[4 + p] = (f32x4){bHN[p], bHN[p], bHN[p], bHN[p]};
        }
        #pragma unroll
        for (int ks = 0; ks < 4; ++ks) {
            #pragma unroll
            for (int q = 0; q < 6; ++q) racc[q] = MFMA16(ah[ks], BH[q][ks], racc[q]);
            #pragma unroll
            for (int q = 0; q < 6; ++q) racc[q] = MFMA16(al[ks], BH[q][ks], racc[q]);
        }

        // 4. gates (xacc = xp(si) + folded biases)
        float hnew[2][4];
        #pragma unroll
        for (int p = 0; p < 2; ++p)
            #pragma unroll
            for (int r = 0; r < 4; ++r) {
                float gr = sigm_(racc[0 + p][r] + xacc[0 + p][r]);
                float gz = sigm_(racc[2 + p][r] + xacc[2 + p][r]);
                float gn = tanhf_(xacc[4 + p][r] + gr * racc[4 + p][r]);
                float hv = gn + gz * (hold[p][r] - gn);
                hnew[p][r] = hv;
                hold[p][r] = hv;
            }

        // 5. xproj for si+1 (off-chain; consumed next iteration)
        #pragma unroll
        for (int p = 0; p < 2; ++p) {
            xacc[0 + p] = (f32x4){bRs[p], bRs[p], bRs[p], bRs[p]};
            xacc[2 + p] = (f32x4){bZs[p], bZs[p], bZs[p], bZs[p]};
            xacc[4 + p] = (f32x4){bIN[p], bIN[p], bIN[p], bIN[p]};
        }
        #pragma unroll
        for (int ks = 0; ks < 4; ++ks) {
            #pragma unroll
            for (int q = 0; q < 6; ++q)
                xacc[q] = MFMA16(xh[ks], WI[q][ks], xacc[q]);
        }

        // 6. h split -> hA[hn] (lanes l4<2 cover 8 batches x 2 cols each)
        if (l4 < 2) {
            #pragma unroll
            for (int r = 0; r < 4; ++r) {
                int b = l4 * 4 + r;
                #pragma unroll
                for (int p = 0; p < 2; ++p) {
                    short hi = bf16_rne(hold[p][r]);
                    short lo = bf16_rne(hold[p][r] - bf16_tof(hi));
                    hA[hn][0][b][col0 + p * 64] = hi;
                    hA[hn][1][b][col0 + p * 64] = lo;
                }
            }
            // 7. out stores (scatter to t, zero-masked; fire-and-forget)
            #pragma unroll
            for (int r = 0; r < 4; ++r) {
                int t = tcur[r];
                int valid = t < lenr[r];
                float* op = &out[((size_t)(c * BB + bbase + l4 * 4 + r) * LL + t) * HH + col0];
                op[0]  = valid ? hnew[0][r] : 0.0f;
                op[64] = valid ? hnew[1][r] : 0.0f;
            }
        }
        #pragma unroll
        for (int r = 0; r < 4; ++r) tcur[r] = (tcur[r] + 1 == LL) ? 0 : tcur[r] + 1;

        // 8. stage x(si+2) -> xs[hb] (raw regs loaded last iter; vmcnt auto)
        *(uint2*)&xs[hb][bsl][k0s] = pack4(xraw);
        // 9. issue x(si+3) raw load (mod-L wrap keeps it in-bounds)
        xraw = *(const float4*)(srow + (size_t)txs * (CC * HH));
        txs = (txs + 1 == LL) ? 0 : txs + 1;

        // 10. lgkm-only drain + raw barrier (out stores/x loads stay in flight)
        asm volatile("s_waitcnt lgkmcnt(0)" ::: "memory");
        __builtin_amdgcn_s_barrier();
        __builtin_amdgcn_sched_barrier(0);
        asm volatile("" ::: "memory");
    }
}

extern "C" void kernel_launch(void* const* d_in, const int* in_sizes, int n_in,
                              void* d_out, int out_size, void* d_ws, size_t ws_size,
                              hipStream_t stream) {
    const float* seqs  = (const float*)d_in[0];
    const unsigned char* tmask = (const unsigned char*)d_in[1];
    // d_in[2] = attention_mask (all false, unused)
    const float* W_ih  = (const float*)d_in[3];
    const float* W_hh  = (const float*)d_in[4];
    const float* b_ih  = (const float*)d_in[5];
    const float* b_hh  = (const float*)d_in[6];
    float* out = (float*)d_out;

    char* ws = (char*)d_ws;
    int*   lens   = (int*)(ws);                       // 1 KB
    short* wih_hi = (short*)(ws + 1024);              // 384 KB
    short* whh_hi = (short*)(ws + 1024 + 393216);     // 384 KB

    compute_lens_kernel<<<1, BB, 0, stream>>>(tmask, lens);
    wsplit_kernel<<<768, 256, 0, stream>>>(W_ih, W_hh, wih_hi, whh_hi);

    gru_fused_kernel<<<dim3(32, CC), 256, 0, stream>>>(
        seqs, lens, wih_hi, whh_hi, b_ih, b_hh, out);
}

// Round 10
// 319.664 us; speedup vs baseline: 1.0066x; 1.0066x over previous
//
#include <hip/hip_runtime.h>
#include <hip/hip_bf16.h>

#define BB 256
#define LL 200
#define CC 4
#define HH 128
#define G3 384

typedef short bf16x8 __attribute__((ext_vector_type(8)));
typedef float f32x4 __attribute__((ext_vector_type(4)));

#define MFMA16(a, b, c) __builtin_amdgcn_mfma_f32_16x16x32_bf16((a), (b), (c), 0, 0, 0)

__device__ __forceinline__ short bf16_rne(float x) {
    union { float f; unsigned u; } v; v.f = x;
    unsigned r = v.u + 0x7FFFu + ((v.u >> 16) & 1u);
    return (short)(r >> 16);
}
__device__ __forceinline__ float bf16_tof(short b) {
    union { unsigned u; float f; } v; v.u = ((unsigned)(unsigned short)b) << 16;
    return v.f;
}
__device__ __forceinline__ float rcp_(float x) { return __builtin_amdgcn_rcpf(x); }
__device__ __forceinline__ float sigm_(float x) { return rcp_(1.0f + __expf(-x)); }
__device__ __forceinline__ float tanhf_(float x) { return 2.0f * rcp_(1.0f + __expf(-2.0f * x)) - 1.0f; }

__device__ __forceinline__ uint2 pack4(float4 v) {
    uint2 p;
    p.x = (unsigned)(unsigned short)bf16_rne(v.x) | ((unsigned)(unsigned short)bf16_rne(v.y) << 16);
    p.y = (unsigned)(unsigned short)bf16_rne(v.z) | ((unsigned)(unsigned short)bf16_rne(v.w) << 16);
    return p;
}

// ---------------------------------------------------------------------------
// lengths from timeline_mask (bool-dtype detection, verified R1-R9)
// ---------------------------------------------------------------------------
__global__ void compute_lens_kernel(const unsigned char* __restrict__ mask8,
                                    int* __restrict__ lens) {
    __shared__ int bad;
    int b = threadIdx.x;
    if (b == 0) bad = 0;
    __syncthreads();
    int cnt8 = 0, prev = 0, mono = 1;
    for (int t = 0; t < LL; ++t) {
        int v = mask8[b * LL + t] ? 1 : 0;
        cnt8 += (v == 0);
        if (v < prev) mono = 0;
        prev = v;
    }
    if (!mono) atomicAdd(&bad, 1);
    __syncthreads();
    int len;
    if (bad == 0) {
        len = cnt8;
    } else {
        const int* m32 = (const int*)mask8;
        int c = 0;
        for (int t = 0; t < LL; ++t) c += (m32[b * LL + t] == 0);
        len = c;
    }
    if (len < 1) len = 1;
    if (len > LL) len = LL;
    lens[b] = len;
}

// ---------------------------------------------------------------------------
// weight split: bf16 hi for W_ih and W_hh
// ---------------------------------------------------------------------------
__global__ void wsplit_kernel(const float* __restrict__ Wih, const float* __restrict__ Whh,
                              short* __restrict__ wih_hi, short* __restrict__ whh_hi) {
    int i = blockIdx.x * 256 + threadIdx.x;   // 768 blocks -> 196608
    wih_hi[i] = bf16_rne(Wih[i]);
    whh_hi[i] = bf16_rne(Whh[i]);
}

// ---------------------------------------------------------------------------
// Fused GRU: grid (32 bt x 4 c) = 128 WGs, 256 thr = 4 waves, M=8 batches.
// KEY CHANGE vs R9: weights are pinned in AGPRs via inline-asm "+a"
// constraints re-asserted INSIDE the loop. Arch VGPRs cap at 256 (operand
// encoding); the 512/lane file is only reachable via AGPRs, and the RA
// never volunteers AGPR parking -- "a"-class pins force it. MFMA reads its
// B operand from AGPRs natively, so steady-state cost is zero.
// Arch-VGPR demand drops to ~160 (working set) -> no spills possible.
// Wave w owns gate-cols {w*16+l15, (w+4)*16+l15} per gate via
//   NT(q) = (q>>1)*8 + w + 4*(q&1),  q = gate*2 + p, q=0..5.
// h: hi+lo shorts in LDS, double-buffered, writer-side split.
// x: hi-only bf16 staged cooperatively into LDS one step ahead; xproj for
//    s+1 computed during step s (off the recurrence chain).
// ---------------------------------------------------------------------------
__global__ __launch_bounds__(256, 1) void gru_fused_kernel(
    const float* __restrict__ seqs,    // (B,L,C,H)
    const int*   __restrict__ lens,    // (B,)
    const short* __restrict__ wih_hi,  // (C,384,128) bf16
    const short* __restrict__ whh_hi,  // (C,384,128) bf16
    const float* __restrict__ b_ih,    // (C,384)
    const float* __restrict__ b_hh,    // (C,384)
    float*       __restrict__ out)     // (C,B,L,H)
{
    const int bt = blockIdx.x;             // 0..31
    const int c  = blockIdx.y;             // 0..3
    const int bbase = bt * 8;
    const int tid = threadIdx.x;           // 0..255
    const int w = tid >> 6;                // wave 0..3
    const int l = tid & 63;
    const int l15 = l & 15, g = l >> 4;
    const int lb  = l15 & 7;               // A-row batch (replicated 2x)
    const int l4  = g;

    __shared__ __align__(16) short hA[2][2][8][136];   // [buf][hi/lo][batch][k]
    __shared__ __align__(16) short xs[2][8][136];      // [buf][batch][k] bf16 hi

    // ---- load weight fragments; AGPR-pin via "a"-class inline asm ----
    // B-frag for NT(q): row NT*16+l15, k = ks*32 + g*8 + j
    bf16x8 BH[6][4], WI[6][4];
    #pragma unroll
    for (int q = 0; q < 6; ++q) {
        const int NT = (q >> 1) * 8 + w + 4 * (q & 1);
        #pragma unroll
        for (int ks = 0; ks < 4; ++ks) {
            size_t off = (size_t)(c * G3 + NT * 16 + l15) * HH + ks * 32 + g * 8;
            BH[q][ks] = *(const bf16x8*)(whh_hi + off);
            WI[q][ks] = *(const bf16x8*)(wih_hi + off);
        }
    }
    #pragma unroll
    for (int q = 0; q < 6; ++q) {
        asm volatile("" : "+a"(BH[q][0]), "+a"(BH[q][1]), "+a"(BH[q][2]), "+a"(BH[q][3]),
                          "+a"(WI[q][0]), "+a"(WI[q][1]), "+a"(WI[q][2]), "+a"(WI[q][3]));
    }

    // ---- stager state: thread stages batch row 2w+(l>>5), 4 floats ----
    const int bsl = 2 * w + (l >> 5);       // 0..7
    const int bs  = bbase + bsl;
    const int k0s = (l & 31) * 4;           // 0..124
    const int lenS = lens[bs];
    const float* srow = seqs + ((size_t)bs * LL * CC + c) * HH + k0s;
    int ts0 = LL - lenS;
    int ts1 = ts0 + 1; if (ts1 >= LL) ts1 -= LL;
    float4 xr0 = *(const float4*)(srow + (size_t)ts0 * (CC * HH));
    float4 xr1 = *(const float4*)(srow + (size_t)ts1 * (CC * HH));
    int txs = ts1 + 1; if (txs >= LL) txs -= LL;   // t for s=2

    // ---- biases (2 cols per lane: col0 = w*16+l15, col1 = col0+64) ----
    const int col0 = w * 16 + l15;
    float bRs[2], bZs[2], bHN[2], bIN[2];
    #pragma unroll
    for (int p = 0; p < 2; ++p) {
        int cp = col0 + p * 64;
        bRs[p] = b_hh[c * G3 + cp]       + b_ih[c * G3 + cp];
        bZs[p] = b_hh[c * G3 + 128 + cp] + b_ih[c * G3 + 128 + cp];
        bHN[p] = b_hh[c * G3 + 256 + cp];
        bIN[p] = b_ih[c * G3 + 256 + cp];
    }

    // ---- per-lane output row state (valid for l4<2: batches l4*4+r) ----
    int lenr[4], tcur[4];
    #pragma unroll
    for (int r = 0; r < 4; ++r) {
        int b = bbase + (l4 & 1) * 4 + r;
        lenr[r] = lens[b];
        tcur[r] = LL - lenr[r];
    }
    float hold[2][4];
    #pragma unroll
    for (int p = 0; p < 2; ++p)
        #pragma unroll
        for (int r = 0; r < 4; ++r) hold[p][r] = 0.f;

    // ---- zero h buffer 0 ----
    for (int i = tid; i < 1088; i += 256) ((int*)hA[0])[i] = 0;

    // ---- stage x(0)->xs[0], x(1)->xs[1] ----
    *(uint2*)&xs[0][bsl][k0s] = pack4(xr0);
    *(uint2*)&xs[1][bsl][k0s] = pack4(xr1);
    __syncthreads();

    // ---- xacc(0) from xs[0] ----
    f32x4 xacc[6];
    #pragma unroll
    for (int p = 0; p < 2; ++p) {
        xacc[0 + p] = (f32x4){bRs[p], bRs[p], bRs[p], bRs[p]};
        xacc[2 + p] = (f32x4){bZs[p], bZs[p], bZs[p], bZs[p]};
        xacc[4 + p] = (f32x4){bIN[p], bIN[p], bIN[p], bIN[p]};
    }
    {
        bf16x8 xh[4];
        #pragma unroll
        for (int ks = 0; ks < 4; ++ks)
            xh[ks] = *(const bf16x8*)&xs[0][lb][ks * 32 + g * 8];
        #pragma unroll
        for (int ks = 0; ks < 4; ++ks) {
            #pragma unroll
            for (int q = 0; q < 6; ++q)
                xacc[q] = MFMA16(xh[ks], WI[q][ks], xacc[q]);
        }
    }
    // issue x(2)
    float4 xraw = *(const float4*)(srow + (size_t)txs * (CC * HH));
    txs = (txs + 1 == LL) ? 0 : txs + 1;

    __syncthreads();   // protect xs[0] from step-0 overwrite

    // =======================  main loop  =======================
    for (int si = 0; si < LL; ++si) {
        const int hb = si & 1, hn = hb ^ 1;

        // 0. re-assert AGPR residency (loop-carried through volatile asm:
        //    not rematerializable, not silently spillable)
        #pragma unroll
        for (int q = 0; q < 6; ++q) {
            asm volatile("" : "+a"(BH[q][0]), "+a"(BH[q][1]), "+a"(BH[q][2]), "+a"(BH[q][3]),
                              "+a"(WI[q][0]), "+a"(WI[q][1]), "+a"(WI[q][2]), "+a"(WI[q][3]));
        }

        // 1. h A-frags (hi+lo)
        bf16x8 ah[4], al[4];
        #pragma unroll
        for (int ks = 0; ks < 4; ++ks) {
            ah[ks] = *(const bf16x8*)&hA[hb][0][lb][ks * 32 + g * 8];
            al[ks] = *(const bf16x8*)&hA[hb][1][lb][ks * 32 + g * 8];
        }
        // 2. x(si+1) A-frags (hi only, pre-staged bf16)
        bf16x8 xh[4];
        #pragma unroll
        for (int ks = 0; ks < 4; ++ks)
            xh[ks] = *(const bf16x8*)&xs[hn][lb][ks * 32 + g * 8];

        // 3. rec MFMAs: racc = (h_hi + h_lo) . W_hh_hi  (dep distance 6)
        f32x4 racc[6];
        #pragma unroll
        for (int p = 0; p < 2; ++p) {
            racc[0 + p] = (f32x4){0.f, 0.f, 0.f, 0.f};
            racc[2 + p] = (f32x4){0.f, 0.f, 0.f, 0.f};
            racc[4 + p] = (f32x4){bHN[p], bHN[p], bHN[p], bHN[p]};
        }
        #pragma unroll
        for (int ks = 0; ks < 4; ++ks) {
            #pragma unroll
            for (int q = 0; q < 6; ++q) racc[q] = MFMA16(ah[ks], BH[q][ks], racc[q]);
            #pragma unroll
            for (int q = 0; q < 6; ++q) racc[q] = MFMA16(al[ks], BH[q][ks], racc[q]);
        }

        // 4. gates (xacc = xp(si) + folded biases)
        float hnew[2][4];
        #pragma unroll
        for (int p = 0; p < 2; ++p)
            #pragma unroll
            for (int r = 0; r < 4; ++r) {
                float gr = sigm_(racc[0 + p][r] + xacc[0 + p][r]);
                float gz = sigm_(racc[2 + p][r] + xacc[2 + p][r]);
                float gn = tanhf_(xacc[4 + p][r] + gr * racc[4 + p][r]);
                float hv = gn + gz * (hold[p][r] - gn);
                hnew[p][r] = hv;
                hold[p][r] = hv;
            }

        // 5. xproj for si+1 (off-chain; consumed next iteration)
        #pragma unroll
        for (int p = 0; p < 2; ++p) {
            xacc[0 + p] = (f32x4){bRs[p], bRs[p], bRs[p], bRs[p]};
            xacc[2 + p] = (f32x4){bZs[p], bZs[p], bZs[p], bZs[p]};
            xacc[4 + p] = (f32x4){bIN[p], bIN[p], bIN[p], bIN[p]};
        }
        #pragma unroll
        for (int ks = 0; ks < 4; ++ks) {
            #pragma unroll
            for (int q = 0; q < 6; ++q)
                xacc[q] = MFMA16(xh[ks], WI[q][ks], xacc[q]);
        }

        // 6. h split -> hA[hn] (lanes l4<2 cover 8 batches x 2 cols each)
        if (l4 < 2) {
            #pragma unroll
            for (int r = 0; r < 4; ++r) {
                int b = l4 * 4 + r;
                #pragma unroll
                for (int p = 0; p < 2; ++p) {
                    short hi = bf16_rne(hold[p][r]);
                    short lo = bf16_rne(hold[p][r] - bf16_tof(hi));
                    hA[hn][0][b][col0 + p * 64] = hi;
                    hA[hn][1][b][col0 + p * 64] = lo;
                }
            }
            // 7. out stores (scatter to t, zero-masked; fire-and-forget)
            #pragma unroll
            for (int r = 0; r < 4; ++r) {
                int t = tcur[r];
                int valid = t < lenr[r];
                float* op = &out[((size_t)(c * BB + bbase + l4 * 4 + r) * LL + t) * HH + col0];
                op[0]  = valid ? hnew[0][r] : 0.0f;
                op[64] = valid ? hnew[1][r] : 0.0f;
            }
        }
        #pragma unroll
        for (int r = 0; r < 4; ++r) tcur[r] = (tcur[r] + 1 == LL) ? 0 : tcur[r] + 1;

        // 8. stage x(si+2) -> xs[hb] (raw regs loaded last iter; vmcnt auto)
        *(uint2*)&xs[hb][bsl][k0s] = pack4(xraw);
        // 9. issue x(si+3) raw load (mod-L wrap keeps it in-bounds)
        xraw = *(const float4*)(srow + (size_t)txs * (CC * HH));
        txs = (txs + 1 == LL) ? 0 : txs + 1;

        // 10. lgkm-only drain + raw barrier (out stores/x loads stay in flight)
        asm volatile("s_waitcnt lgkmcnt(0)" ::: "memory");
        __builtin_amdgcn_s_barrier();
        __builtin_amdgcn_sched_barrier(0);
        asm volatile("" ::: "memory");
    }
}

extern "C" void kernel_launch(void* const* d_in, const int* in_sizes, int n_in,
                              void* d_out, int out_size, void* d_ws, size_t ws_size,
                              hipStream_t stream) {
    const float* seqs  = (const float*)d_in[0];
    const unsigned char* tmask = (const unsigned char*)d_in[1];
    // d_in[2] = attention_mask (all false, unused)
    const float* W_ih  = (const float*)d_in[3];
    const float* W_hh  = (const float*)d_in[4];
    const float* b_ih  = (const float*)d_in[5];
    const float* b_hh  = (const float*)d_in[6];
    float* out = (float*)d_out;

    char* ws = (char*)d_ws;
    int*   lens   = (int*)(ws);                       // 1 KB
    short* wih_hi = (short*)(ws + 1024);              // 384 KB
    short* whh_hi = (short*)(ws + 1024 + 393216);     // 384 KB

    compute_lens_kernel<<<1, BB, 0, stream>>>(tmask, lens);
    wsplit_kernel<<<768, 256, 0, stream>>>(W_ih, W_hh, wih_hi, whh_hi);

    gru_fused_kernel<<<dim3(32, CC), 256, 0, stream>>>(
        seqs, lens, wih_hi, whh_hi, b_ih, b_hh, out);
}

// Round 13
// 270.534 us; speedup vs baseline: 1.1894x; 1.1816x over previous
//
#include <hip/hip_runtime.h>
#include <hip/hip_bf16.h>

#define BB 256
#define LL 200
#define CC 4
#define HH 128
#define G3 384

typedef short bf16x8 __attribute__((ext_vector_type(8)));
typedef float f32x4 __attribute__((ext_vector_type(4)));

#define MFMA16(a, b, c) __builtin_amdgcn_mfma_f32_16x16x32_bf16((a), (b), (c), 0, 0, 0)

__device__ __forceinline__ short bf16_rne(float x) {
    union { float f; unsigned u; } v; v.f = x;
    unsigned r = v.u + 0x7FFFu + ((v.u >> 16) & 1u);
    return (short)(r >> 16);
}
__device__ __forceinline__ float bf16_tof(short b) {
    union { unsigned u; float f; } v; v.u = ((unsigned)(unsigned short)b) << 16;
    return v.f;
}
__device__ __forceinline__ float rcp_(float x) { return __builtin_amdgcn_rcpf(x); }
__device__ __forceinline__ float sigm_(float x) { return rcp_(1.0f + __expf(-x)); }
__device__ __forceinline__ float tanhf_(float x) { return 2.0f * rcp_(1.0f + __expf(-2.0f * x)) - 1.0f; }

__device__ __forceinline__ uint2 pack4(float4 v) {
    uint2 p;
    p.x = (unsigned)(unsigned short)bf16_rne(v.x) | ((unsigned)(unsigned short)bf16_rne(v.y) << 16);
    p.y = (unsigned)(unsigned short)bf16_rne(v.z) | ((unsigned)(unsigned short)bf16_rne(v.w) << 16);
    return p;
}

// ---------------------------------------------------------------------------
// lengths from timeline_mask (bool-dtype detection, verified R1-R10)
// ---------------------------------------------------------------------------
__global__ void compute_lens_kernel(const unsigned char* __restrict__ mask8,
                                    int* __restrict__ lens) {
    __shared__ int bad;
    int b = threadIdx.x;
    if (b == 0) bad = 0;
    __syncthreads();
    int cnt8 = 0, prev = 0, mono = 1;
    for (int t = 0; t < LL; ++t) {
        int v = mask8[b * LL + t] ? 1 : 0;
        cnt8 += (v == 0);
        if (v < prev) mono = 0;
        prev = v;
    }
    if (!mono) atomicAdd(&bad, 1);
    __syncthreads();
    int len;
    if (bad == 0) {
        len = cnt8;
    } else {
        const int* m32 = (const int*)mask8;
        int c = 0;
        for (int t = 0; t < LL; ++t) c += (m32[b * LL + t] == 0);
        len = c;
    }
    if (len < 1) len = 1;
    if (len > LL) len = LL;
    lens[b] = len;
}

// ---------------------------------------------------------------------------
// weight split: bf16 hi for W_ih and W_hh
// ---------------------------------------------------------------------------
__global__ void wsplit_kernel(const float* __restrict__ Wih, const float* __restrict__ Whh,
                              short* __restrict__ wih_hi, short* __restrict__ whh_hi) {
    int i = blockIdx.x * 256 + threadIdx.x;   // 768 blocks -> 196608
    wih_hi[i] = bf16_rne(Wih[i]);
    whh_hi[i] = bf16_rne(Whh[i]);
}

// ---------------------------------------------------------------------------
// Fused GRU: grid (16 bt x 4 c) = 64 WGs, 512 thr = 8 waves = 2 waves/SIMD.
// KEY CHANGES vs R9/R10 (which were MFMA+VALU bound at TLP=1):
//  - M=16 real batches/WG: no A-row duplication -> per-lane VALU halves
//    (4 h-values/lane, no divergent split), same 288 MFMA/WG/step.
//  - 8 waves -> 2 waves/SIMD: one wave's gates/VALU overlaps the other's
//    MFMAs (m114: separate pipes). __launch_bounds__(512,2) caps combined
//    VGPR+AGPR at 256/wave so the 8-wave WG is schedulable.
//  - Wave w owns cols [16w,16w+16) of each gate: NT(gate) = gate*8 + w.
//    BH (rec weights, on-chain) = 48 regs, AGPR-pinned in-loop.
//    WI (xproj weights, off-chain) = 48 regs, free-floating.
//  - Per-ks JIT A-frag reads keep the live VGPR window small.
// h: hi+lo shorts in LDS, double-buffered; x: hi-only bf16 staged one step
// ahead; xproj(s+1) computed during step s; one raw barrier/step (lgkm-only).
// ---------------------------------------------------------------------------
__global__ __launch_bounds__(512, 2) void gru_fused_kernel(
    const float* __restrict__ seqs,    // (B,L,C,H)
    const int*   __restrict__ lens,    // (B,)
    const short* __restrict__ wih_hi,  // (C,384,128) bf16
    const short* __restrict__ whh_hi,  // (C,384,128) bf16
    const float* __restrict__ b_ih,    // (C,384)
    const float* __restrict__ b_hh,    // (C,384)
    float*       __restrict__ out)     // (C,B,L,H)
{
    const int bt = blockIdx.x;             // 0..15
    const int c  = blockIdx.y;             // 0..3
    const int bbase = bt * 16;
    const int tid = threadIdx.x;           // 0..511
    const int w = tid >> 6;                // wave 0..7
    const int l = tid & 63;
    const int l15 = l & 15, g = l >> 4;    // A-row = l15, k-group = g

    __shared__ __align__(16) short hA[2][2][16][136];  // [buf][hi/lo][batch][k] 17KB
    __shared__ __align__(16) short xs[2][16][136];     // [buf][batch][k] bf16 hi 8.5KB

    // ---- weight fragments: B-frag row NT*16+l15, k = ks*32 + g*8 + j ----
    // NT(gate) = gate*8 + w  -> this wave computes cols [16w,16w+16) of each gate
    bf16x8 BH[3][4], WI[3][4];
    #pragma unroll
    for (int q = 0; q < 3; ++q) {
        const int NT = q * 8 + w;
        #pragma unroll
        for (int ks = 0; ks < 4; ++ks) {
            size_t off = (size_t)(c * G3 + NT * 16 + l15) * HH + ks * 32 + g * 8;
            BH[q][ks] = *(const bf16x8*)(whh_hi + off);
            WI[q][ks] = *(const bf16x8*)(wih_hi + off);
        }
    }
    // pin the on-chain rec weights into AGPRs (48 regs)
    #pragma unroll
    for (int q = 0; q < 3; ++q)
        asm volatile("" : "+a"(BH[q][0]), "+a"(BH[q][1]), "+a"(BH[q][2]), "+a"(BH[q][3]));

    // ---- stager: thread stages batch row tid>>5 (16 rows x 32 thr), 4 floats ----
    const int bsl = tid >> 5;               // 0..15
    const int bs  = bbase + bsl;
    const int k0s = (tid & 31) * 4;         // 0..124
    const int lenS = lens[bs];
    const float* srow = seqs + ((size_t)bs * LL * CC + c) * HH + k0s;
    int ts0 = LL - lenS;
    int ts1 = ts0 + 1; if (ts1 >= LL) ts1 -= LL;
    float4 xr0 = *(const float4*)(srow + (size_t)ts0 * (CC * HH));
    float4 xr1 = *(const float4*)(srow + (size_t)ts1 * (CC * HH));
    int txs = ts1 + 1; if (txs >= LL) txs -= LL;   // t for s=2

    // ---- biases (one col per lane) ----
    const int col0 = w * 16 + l15;
    const float bRs = b_hh[c * G3 + col0]       + b_ih[c * G3 + col0];
    const float bZs = b_hh[c * G3 + 128 + col0] + b_ih[c * G3 + 128 + col0];
    const float bHN = b_hh[c * G3 + 256 + col0];
    const float bIN = b_ih[c * G3 + 256 + col0];

    // ---- per-lane output rows: batches bbase + g*4 + r (C/D row = g*4+r) ----
    int lenr[4], tcur[4];
    #pragma unroll
    for (int r = 0; r < 4; ++r) {
        lenr[r] = lens[bbase + g * 4 + r];
        tcur[r] = LL - lenr[r];
    }
    float hold[4] = { 0.f, 0.f, 0.f, 0.f };

    // ---- zero h buffer 0 ([2][16][136] = 2176 dwords) ----
    for (int i = tid; i < 2176; i += 512) ((int*)hA[0])[i] = 0;

    // ---- stage x(0)->xs[0], x(1)->xs[1] ----
    *(uint2*)&xs[0][bsl][k0s] = pack4(xr0);
    *(uint2*)&xs[1][bsl][k0s] = pack4(xr1);
    __syncthreads();

    // ---- xacc(0) from xs[0] ----
    f32x4 xacc[3];
    xacc[0] = (f32x4){bRs, bRs, bRs, bRs};
    xacc[1] = (f32x4){bZs, bZs, bZs, bZs};
    xacc[2] = (f32x4){bIN, bIN, bIN, bIN};
    #pragma unroll
    for (int ks = 0; ks < 4; ++ks) {
        bf16x8 xh = *(const bf16x8*)&xs[0][l15][ks * 32 + g * 8];
        #pragma unroll
        for (int q = 0; q < 3; ++q)
            xacc[q] = MFMA16(xh, WI[q][ks], xacc[q]);
    }
    // issue x(2)
    float4 xraw = *(const float4*)(srow + (size_t)txs * (CC * HH));
    txs = (txs + 1 == LL) ? 0 : txs + 1;

    __syncthreads();   // protect xs[0] from step-0 overwrite

    // =======================  main loop  =======================
    for (int si = 0; si < LL; ++si) {
        const int hb = si & 1, hn = hb ^ 1;

        // 0. re-assert AGPR residency of rec weights
        #pragma unroll
        for (int q = 0; q < 3; ++q)
            asm volatile("" : "+a"(BH[q][0]), "+a"(BH[q][1]), "+a"(BH[q][2]), "+a"(BH[q][3]));

        // 1. rec MFMAs (per-ks JIT A-frag reads, dep distance 3)
        f32x4 racc[3];
        racc[0] = (f32x4){0.f, 0.f, 0.f, 0.f};
        racc[1] = (f32x4){0.f, 0.f, 0.f, 0.f};
        racc[2] = (f32x4){bHN, bHN, bHN, bHN};
        #pragma unroll
        for (int ks = 0; ks < 4; ++ks) {
            bf16x8 ah = *(const bf16x8*)&hA[hb][0][l15][ks * 32 + g * 8];
            bf16x8 al = *(const bf16x8*)&hA[hb][1][l15][ks * 32 + g * 8];
            #pragma unroll
            for (int q = 0; q < 3; ++q) racc[q] = MFMA16(ah, BH[q][ks], racc[q]);
            #pragma unroll
            for (int q = 0; q < 3; ++q) racc[q] = MFMA16(al, BH[q][ks], racc[q]);
        }

        // 2. gates (xacc = xp(si) + folded biases); 4 h-values per lane
        float hnew[4];
        #pragma unroll
        for (int r = 0; r < 4; ++r) {
            float gr = sigm_(racc[0][r] + xacc[0][r]);
            float gz = sigm_(racc[1][r] + xacc[1][r]);
            float gn = tanhf_(xacc[2][r] + gr * racc[2][r]);
            float hv = gn + gz * (hold[r] - gn);
            hnew[r] = hv;
            hold[r] = hv;
        }

        // 3. xproj for si+1 (off-chain, overlaps other wave's rec via TLP)
        xacc[0] = (f32x4){bRs, bRs, bRs, bRs};
        xacc[1] = (f32x4){bZs, bZs, bZs, bZs};
        xacc[2] = (f32x4){bIN, bIN, bIN, bIN};
        #pragma unroll
        for (int ks = 0; ks < 4; ++ks) {
            bf16x8 xh = *(const bf16x8*)&xs[hn][l15][ks * 32 + g * 8];
            #pragma unroll
            for (int q = 0; q < 3; ++q)
                xacc[q] = MFMA16(xh, WI[q][ks], xacc[q]);
        }

        // 4. h split -> hA[hn]: every lane writes its 4 (row=g*4+r, col0)
        #pragma unroll
        for (int r = 0; r < 4; ++r) {
            short hi = bf16_rne(hold[r]);
            short lo = bf16_rne(hold[r] - bf16_tof(hi));
            hA[hn][0][g * 4 + r][col0] = hi;
            hA[hn][1][g * 4 + r][col0] = lo;
        }

        // 5. out stores (scatter to t, zero-masked; fire-and-forget)
        #pragma unroll
        for (int r = 0; r < 4; ++r) {
            int t = tcur[r];
            int valid = t < lenr[r];
            out[((size_t)(c * BB + bbase + g * 4 + r) * LL + t) * HH + col0]
                = valid ? hnew[r] : 0.0f;
            tcur[r] = (t + 1 == LL) ? 0 : t + 1;
        }

        // 6. stage x(si+2) -> xs[hb] (raw regs loaded last iter; vmcnt auto)
        *(uint2*)&xs[hb][bsl][k0s] = pack4(xraw);
        // 7. issue x(si+3) raw load (mod-L wrap keeps it in-bounds)
        xraw = *(const float4*)(srow + (size_t)txs * (CC * HH));
        txs = (txs + 1 == LL) ? 0 : txs + 1;

        // 8. lgkm-only drain + raw barrier (out stores/x loads stay in flight)
        asm volatile("s_waitcnt lgkmcnt(0)" ::: "memory");
        __builtin_amdgcn_s_barrier();
        __builtin_amdgcn_sched_barrier(0);
        asm volatile("" ::: "memory");
    }
}

extern "C" void kernel_launch(void* const* d_in, const int* in_sizes, int n_in,
                              void* d_out, int out_size, void* d_ws, size_t ws_size,
                              hipStream_t stream) {
    const float* seqs  = (const float*)d_in[0];
    const unsigned char* tmask = (const unsigned char*)d_in[1];
    // d_in[2] = attention_mask (all false, unused)
    const float* W_ih  = (const float*)d_in[3];
    const float* W_hh  = (const float*)d_in[4];
    const float* b_ih  = (const float*)d_in[5];
    const float* b_hh  = (const float*)d_in[6];
    float* out = (float*)d_out;

    char* ws = (char*)d_ws;
    int*   lens   = (int*)(ws);                       // 1 KB
    short* wih_hi = (short*)(ws + 1024);              // 384 KB
    short* whh_hi = (short*)(ws + 1024 + 393216);     // 384 KB

    compute_lens_kernel<<<1, BB, 0, stream>>>(tmask, lens);
    wsplit_kernel<<<768, 256, 0, stream>>>(W_ih, W_hh, wih_hi, whh_hi);

    gru_fused_kernel<<<dim3(16, CC), 512, 0, stream>>>(
        seqs, lens, wih_hi, whh_hi, b_ih, b_hh, out);
}